// Round 1
// baseline (172.536 us; speedup 1.0000x reference)
//
#include <hip/hip_runtime.h>
#include <hip/hip_bf16.h>

// Problem constants
#define B_ 16
#define C_ 512
#define H_ 28
#define W_ 28
#define TPREV 15
#define TT 16          // TPREV + 1
#define HEADS_ 16
#define DHEAD 32       // C_/HEADS_
#define HW 784         // H_*W_
#define HW4 196        // HW/4
#define NORM 0.17677669529663687f  // 1/sqrt(32)

// ---------------- Kernel 1: global average pool  y[b,c] = mean_hw x ----------------
__global__ __launch_bounds__(64) void pool_kernel(const float* __restrict__ x,
                                                  float* __restrict__ y) {
    const int bc = blockIdx.x;                    // 0..B*C-1
    const float4* __restrict__ xr = (const float4*)(x + (size_t)bc * HW);
    const int lane = threadIdx.x;                 // 64 lanes
    float s = 0.0f;
    for (int i = lane; i < HW4; i += 64) {
        float4 v = xr[i];
        s += v.x + v.y + v.z + v.w;
    }
    #pragma unroll
    for (int off = 32; off > 0; off >>= 1) s += __shfl_down(s, off);
    if (lane == 0) y[bc] = s * (1.0f / (float)HW);
}

// ---------------- Kernel 2: ECA conv1d Q/k, K concat, attention softmax ----------------
__global__ __launch_bounds__(256) void attn_kernel(const float* __restrict__ y,
                                                   const float* __restrict__ prevK,
                                                   const float* __restrict__ wq,
                                                   const float* __restrict__ wk,
                                                   float* __restrict__ Kout,
                                                   float* __restrict__ att) {
    const int b = blockIdx.x;
    const int tid = threadIdx.x;
    __shared__ float y_s[C_];
    __shared__ float Q_s[C_];
    __shared__ float K_s[TT * 513];       // padded stride to avoid bank conflicts
    __shared__ float logit[HEADS_][17];

    // load y row
    y_s[tid]       = y[b * C_ + tid];
    y_s[tid + 256] = y[b * C_ + tid + 256];

    const float q0 = wq[0], q1 = wq[1], q2 = wq[2], q3 = wq[3], q4 = wq[4];
    const float k0 = wk[0], k1 = wk[1], k2 = wk[2], k3 = wk[3], k4 = wk[4];

    // stage prev_K into LDS
    for (int i = tid; i < TPREV * C_; i += 256) {
        int t = i >> 9, c = i & (C_ - 1);
        K_s[t * 513 + c] = prevK[((size_t)b * TPREV + t) * C_ + c];
    }
    __syncthreads();

    // conv1d over channels (SAME, zero pad), cross-correlation
    for (int c = tid; c < C_; c += 256) {
        float a0 = (c >= 2)      ? y_s[c - 2] : 0.0f;
        float a1 = (c >= 1)      ? y_s[c - 1] : 0.0f;
        float a2 = y_s[c];
        float a3 = (c <= C_ - 2) ? y_s[c + 1] : 0.0f;
        float a4 = (c <= C_ - 3) ? y_s[c + 2] : 0.0f;
        Q_s[c]             = a0 * q0 + a1 * q1 + a2 * q2 + a3 * q3 + a4 * q4;
        K_s[TPREV * 513 + c] = a0 * k0 + a1 * k1 + a2 * k2 + a3 * k3 + a4 * k4;
    }
    __syncthreads();

    // write K output (concat prev_K, k)
    for (int i = tid; i < TT * C_; i += 256) {
        int t = i >> 9, c = i & (C_ - 1);
        Kout[((size_t)b * TT + t) * C_ + c] = K_s[t * 513 + c];
    }

    // logits: thread (g,t)
    const int g = tid >> 4, t = tid & 15;
    float s = 0.0f;
    #pragma unroll
    for (int d = 0; d < DHEAD; ++d)
        s += Q_s[g * DHEAD + d] * K_s[t * 513 + g * DHEAD + d];
    s *= NORM;
    logit[g][t] = s;
    __syncthreads();

    float m = -1e30f;
    #pragma unroll
    for (int j = 0; j < TT; ++j) m = fmaxf(m, logit[g][j]);
    float sum = 0.0f;
    #pragma unroll
    for (int j = 0; j < TT; ++j) sum += __expf(logit[g][j] - m);
    att[((size_t)b * HEADS_ + g) * TT + t] = __expf(s - m) / sum;
}

// ---------------- Kernel 3: fused depthwise conv + V concat + attention PV ----------------
__global__ __launch_bounds__(256) void fuse_kernel(const float* __restrict__ x,
                                                   const float* __restrict__ prevV,
                                                   const float* __restrict__ wv,
                                                   const float* __restrict__ att,
                                                   float* __restrict__ out,
                                                   float* __restrict__ Vout) {
    const int i = blockIdx.x * 256 + threadIdx.x;   // 0 .. B*C*HW4-1
    const int p4 = i % HW4;
    const int bc = i / HW4;
    const int c  = bc & (C_ - 1);
    const int b  = bc >> 9;
    const int p  = p4 * 4;
    const int h  = p / W_;
    const int w0 = p % W_;          // multiple of 4 (28 % 4 == 0)
    const int g  = c >> 5;

    // ---- depthwise 3x3 conv (SAME, zero pad) for 4 consecutive pixels ----
    const float* __restrict__ xbc = x + (size_t)bc * HW;
    float r[3][6];
    #pragma unroll
    for (int ry = 0; ry < 3; ++ry) {
        const int hh = h - 1 + ry;
        if (hh < 0 || hh >= H_) {
            #pragma unroll
            for (int j = 0; j < 6; ++j) r[ry][j] = 0.0f;
        } else {
            const float* row = xbc + hh * W_;
            float4 mid = *(const float4*)(row + w0);
            r[ry][1] = mid.x; r[ry][2] = mid.y; r[ry][3] = mid.z; r[ry][4] = mid.w;
            r[ry][0] = (w0 > 0)        ? row[w0 - 1] : 0.0f;
            r[ry][5] = (w0 + 4 < W_)   ? row[w0 + 4] : 0.0f;
        }
    }
    float wv9[9];
    #pragma unroll
    for (int k = 0; k < 9; ++k) wv9[k] = wv[c * 9 + k];

    float4 v4;
    {
        float acc[4];
        #pragma unroll
        for (int j = 0; j < 4; ++j) {
            float s = 0.0f;
            #pragma unroll
            for (int ky = 0; ky < 3; ++ky)
                #pragma unroll
                for (int kx = 0; kx < 3; ++kx)
                    s = fmaf(r[ky][j + kx], wv9[ky * 3 + kx], s);
            acc[j] = s;
        }
        v4.x = acc[0]; v4.y = acc[1]; v4.z = acc[2]; v4.w = acc[3];
    }

    // ---- attention row ----
    const float* __restrict__ arow = att + ((size_t)b * HEADS_ + g) * TT;

    float4* __restrict__ Vo = (float4*)Vout;
    const float4* __restrict__ Pv = (const float4*)prevV;

    // t = 15 (new v)
    {
        const float a = arow[TPREV];
        Vo[(((size_t)b * TT + TPREV) * C_ + c) * HW4 + p4] = v4;
        v4.x *= a; v4.y *= a; v4.z *= a; v4.w *= a;   // acc = a15 * v
    }
    float4 acc = v4;

    #pragma unroll
    for (int t = 0; t < TPREV; ++t) {
        float4 pv = Pv[(((size_t)b * TPREV + t) * C_ + c) * HW4 + p4];
        Vo[(((size_t)b * TT + t) * C_ + c) * HW4 + p4] = pv;
        const float a = arow[t];
        acc.x = fmaf(a, pv.x, acc.x);
        acc.y = fmaf(a, pv.y, acc.y);
        acc.z = fmaf(a, pv.z, acc.z);
        acc.w = fmaf(a, pv.w, acc.w);
    }
    ((float4*)out)[(size_t)bc * HW4 + p4] = acc;
}

extern "C" void kernel_launch(void* const* d_in, const int* in_sizes, int n_in,
                              void* d_out, int out_size, void* d_ws, size_t ws_size,
                              hipStream_t stream) {
    const float* x     = (const float*)d_in[0];
    const float* prevK = (const float*)d_in[1];
    const float* prevV = (const float*)d_in[2];
    const float* wq    = (const float*)d_in[3];
    const float* wk    = (const float*)d_in[4];
    const float* wv    = (const float*)d_in[5];

    float* out  = (float*)d_out;                       // [B,C,H,W]
    float* Kout = out + (size_t)B_ * C_ * HW;          // [B,TT,C]
    float* Vout = Kout + (size_t)B_ * TT * C_;         // [B,TT,C,H,W]

    float* y_ws   = (float*)d_ws;                      // B*C
    float* att_ws = y_ws + B_ * C_;                    // B*HEADS*TT

    pool_kernel<<<B_ * C_, 64, 0, stream>>>(x, y_ws);
    attn_kernel<<<B_, 256, 0, stream>>>(y_ws, prevK, wq, wk, Kout, att_ws);

    const int total4 = B_ * C_ * HW4;                  // 1,605,632
    fuse_kernel<<<total4 / 256, 256, 0, stream>>>(x, prevV, wv, att_ws, out, Vout);
}

// Round 3
// 163.391 us; speedup vs baseline: 1.0560x; 1.0560x over previous
//
#include <hip/hip_runtime.h>
#include <hip/hip_bf16.h>

// Problem constants
#define B_ 16
#define C_ 512
#define H_ 28
#define W_ 28
#define TPREV 15
#define TT 16          // TPREV + 1
#define HEADS_ 16
#define DHEAD 32       // C_/HEADS_
#define HW 784         // H_*W_
#define HW4 196        // HW/4
#define NORM 0.17677669529663687f  // 1/sqrt(32)

typedef float f32x4 __attribute__((ext_vector_type(4)));  // native vector for nontemporal builtins

// ---------------- Kernel 1: global average pool  y[b,c] = mean_hw x ----------------
__global__ __launch_bounds__(64) void pool_kernel(const float* __restrict__ x,
                                                  float* __restrict__ y) {
    const int bc = blockIdx.x;                    // 0..B*C-1
    const f32x4* __restrict__ xr = (const f32x4*)(x + (size_t)bc * HW);
    const int lane = threadIdx.x;                 // 64 lanes
    float s = 0.0f;
    for (int i = lane; i < HW4; i += 64) {
        f32x4 v = xr[i];
        s += v.x + v.y + v.z + v.w;
    }
    #pragma unroll
    for (int off = 32; off > 0; off >>= 1) s += __shfl_down(s, off);
    if (lane == 0) y[bc] = s * (1.0f / (float)HW);
}

// ---------------- Kernel 2: ECA conv1d Q/k, K concat, attention softmax ----------------
__global__ __launch_bounds__(256) void attn_kernel(const float* __restrict__ y,
                                                   const float* __restrict__ prevK,
                                                   const float* __restrict__ wq,
                                                   const float* __restrict__ wk,
                                                   float* __restrict__ Kout,
                                                   float* __restrict__ att) {
    const int b = blockIdx.x;
    const int tid = threadIdx.x;
    __shared__ float y_s[C_];
    __shared__ float Q_s[C_];
    __shared__ float K_s[TT * 513];       // padded stride to avoid bank conflicts
    __shared__ float logit[HEADS_][17];

    // load y row
    y_s[tid]       = y[b * C_ + tid];
    y_s[tid + 256] = y[b * C_ + tid + 256];

    const float q0 = wq[0], q1 = wq[1], q2 = wq[2], q3 = wq[3], q4 = wq[4];
    const float k0 = wk[0], k1 = wk[1], k2 = wk[2], k3 = wk[3], k4 = wk[4];

    // stage prev_K into LDS
    for (int i = tid; i < TPREV * C_; i += 256) {
        int t = i >> 9, c = i & (C_ - 1);
        K_s[t * 513 + c] = prevK[((size_t)b * TPREV + t) * C_ + c];
    }
    __syncthreads();

    // conv1d over channels (SAME, zero pad), cross-correlation
    for (int c = tid; c < C_; c += 256) {
        float a0 = (c >= 2)      ? y_s[c - 2] : 0.0f;
        float a1 = (c >= 1)      ? y_s[c - 1] : 0.0f;
        float a2 = y_s[c];
        float a3 = (c <= C_ - 2) ? y_s[c + 1] : 0.0f;
        float a4 = (c <= C_ - 3) ? y_s[c + 2] : 0.0f;
        Q_s[c]               = a0 * q0 + a1 * q1 + a2 * q2 + a3 * q3 + a4 * q4;
        K_s[TPREV * 513 + c] = a0 * k0 + a1 * k1 + a2 * k2 + a3 * k3 + a4 * k4;
    }
    __syncthreads();

    // write K output (concat prev_K, k)
    for (int i = tid; i < TT * C_; i += 256) {
        int t = i >> 9, c = i & (C_ - 1);
        Kout[((size_t)b * TT + t) * C_ + c] = K_s[t * 513 + c];
    }

    // logits: thread (g,t)
    const int g = tid >> 4, t = tid & 15;
    float s = 0.0f;
    #pragma unroll
    for (int d = 0; d < DHEAD; ++d)
        s += Q_s[g * DHEAD + d] * K_s[t * 513 + g * DHEAD + d];
    s *= NORM;
    logit[g][t] = s;
    __syncthreads();

    float m = -1e30f;
    #pragma unroll
    for (int j = 0; j < TT; ++j) m = fmaxf(m, logit[g][j]);
    float sum = 0.0f;
    #pragma unroll
    for (int j = 0; j < TT; ++j) sum += __expf(logit[g][j] - m);
    att[((size_t)b * HEADS_ + g) * TT + t] = __expf(s - m) / sum;
}

// ---------------- Kernel 3: fused depthwise conv + V concat + attention PV ----------------
__global__ __launch_bounds__(256) void fuse_kernel(const float* __restrict__ x,
                                                   const float* __restrict__ prevV,
                                                   const float* __restrict__ wv,
                                                   const float* __restrict__ att,
                                                   float* __restrict__ out,
                                                   float* __restrict__ Vout) {
    const int i = blockIdx.x * 256 + threadIdx.x;   // 0 .. B*C*HW4-1
    const int p4 = i % HW4;
    const int bc = i / HW4;
    const int c  = bc & (C_ - 1);
    const int b  = bc >> 9;
    const int p  = p4 * 4;
    const int h  = p / W_;
    const int w0 = p % W_;          // multiple of 4 (28 % 4 == 0)
    const int g  = c >> 5;

    // ---- depthwise 3x3 conv (SAME, zero pad) for 4 consecutive pixels ----
    const float* __restrict__ xbc = x + (size_t)bc * HW;
    float r[3][6];
    #pragma unroll
    for (int ry = 0; ry < 3; ++ry) {
        const int hh = h - 1 + ry;
        if (hh < 0 || hh >= H_) {
            #pragma unroll
            for (int j = 0; j < 6; ++j) r[ry][j] = 0.0f;
        } else {
            const float* row = xbc + hh * W_;
            f32x4 mid = *(const f32x4*)(row + w0);
            r[ry][1] = mid.x; r[ry][2] = mid.y; r[ry][3] = mid.z; r[ry][4] = mid.w;
            r[ry][0] = (w0 > 0)        ? row[w0 - 1] : 0.0f;
            r[ry][5] = (w0 + 4 < W_)   ? row[w0 + 4] : 0.0f;
        }
    }
    float wv9[9];
    #pragma unroll
    for (int k = 0; k < 9; ++k) wv9[k] = wv[c * 9 + k];

    f32x4 v4;
    {
        float acc[4];
        #pragma unroll
        for (int j = 0; j < 4; ++j) {
            float s = 0.0f;
            #pragma unroll
            for (int ky = 0; ky < 3; ++ky)
                #pragma unroll
                for (int kx = 0; kx < 3; ++kx)
                    s = fmaf(r[ky][j + kx], wv9[ky * 3 + kx], s);
            acc[j] = s;
        }
        v4.x = acc[0]; v4.y = acc[1]; v4.z = acc[2]; v4.w = acc[3];
    }

    // ---- attention row ----
    const float* __restrict__ arow = att + ((size_t)b * HEADS_ + g) * TT;

    f32x4* __restrict__ Vo = (f32x4*)Vout;
    const f32x4* __restrict__ Pv = (const f32x4*)prevV;

    // t = 15 (new v): streaming store, no reuse -> nontemporal
    {
        const float a = arow[TPREV];
        __builtin_nontemporal_store(v4, &Vo[(((size_t)b * TT + TPREV) * C_ + c) * HW4 + p4]);
        v4 *= a;                      // acc = a15 * v
    }
    f32x4 acc = v4;

    #pragma unroll
    for (int t = 0; t < TPREV; ++t) {
        f32x4 pv = __builtin_nontemporal_load(&Pv[(((size_t)b * TPREV + t) * C_ + c) * HW4 + p4]);
        __builtin_nontemporal_store(pv, &Vo[(((size_t)b * TT + t) * C_ + c) * HW4 + p4]);
        const float a = arow[t];
        acc.x = fmaf(a, pv.x, acc.x);
        acc.y = fmaf(a, pv.y, acc.y);
        acc.z = fmaf(a, pv.z, acc.z);
        acc.w = fmaf(a, pv.w, acc.w);
    }
    __builtin_nontemporal_store(acc, &((f32x4*)out)[(size_t)bc * HW4 + p4]);
}

extern "C" void kernel_launch(void* const* d_in, const int* in_sizes, int n_in,
                              void* d_out, int out_size, void* d_ws, size_t ws_size,
                              hipStream_t stream) {
    const float* x     = (const float*)d_in[0];
    const float* prevK = (const float*)d_in[1];
    const float* prevV = (const float*)d_in[2];
    const float* wq    = (const float*)d_in[3];
    const float* wk    = (const float*)d_in[4];
    const float* wv    = (const float*)d_in[5];

    float* out  = (float*)d_out;                       // [B,C,H,W]
    float* Kout = out + (size_t)B_ * C_ * HW;          // [B,TT,C]
    float* Vout = Kout + (size_t)B_ * TT * C_;         // [B,TT,C,H,W]

    float* y_ws   = (float*)d_ws;                      // B*C
    float* att_ws = y_ws + B_ * C_;                    // B*HEADS*TT

    pool_kernel<<<B_ * C_, 64, 0, stream>>>(x, y_ws);
    attn_kernel<<<B_, 256, 0, stream>>>(y_ws, prevK, wq, wk, Kout, att_ws);

    const int total4 = B_ * C_ * HW4;                  // 1,605,632
    fuse_kernel<<<total4 / 256, 256, 0, stream>>>(x, prevV, wv, att_ws, out, Vout);
}